// Round 5
// baseline (567.647 us; speedup 1.0000x reference)
//
#include <hip/hip_runtime.h>
#include <math.h>

#define NN 10000
#define NI 1000
#define NF 8600
#define NE 80000
#define NC 16
#define NB 64
#define NS (NI + NF)        // 9600 possible src nodes
#define NLAYERS 6
#define LN_EPS 1e-5f
#define XEBASE (NN * NB)    // xeD starts here inside xbuf (element offset)
#define PF 16               // gather-prefetch depth (loads in flight per wave)

#define NODE_BLOCKS ((NF + 3) / 4)       // 2150 blocks x 4 waves
#define EDGE_BLOCKS ((NS + 7) / 8)       // 1200 blocks x 8 waves
#define TILE_BLOCKS ((NN + 63) / 64)     // 157

typedef float f32x4 __attribute__((ext_vector_type(4)));

__device__ __forceinline__ float elu_fast(float x) {
    // exp(x)-1 for x<=0: abs err ~1ulp(1.0) ~6e-8, fine vs 0.17 threshold
    return x > 0.0f ? x : __expf(x) - 1.0f;
}

// ---- tiled transpose: xbuf[n*64+b] = x[b*NN+n] ----
__global__ __launch_bounds__(256) void k_transpose(const float* __restrict__ x,
                                                   float* __restrict__ xT) {
    __shared__ float t[64][65];
    int n0 = blockIdx.x * 64;
    int lane = threadIdx.x & 63, w = threadIdx.x >> 6;
    int n = n0 + lane;
    for (int bb = w; bb < 64; bb += 4)
        t[bb][lane] = (n < NN) ? x[(size_t)bb * NN + n] : 0.f;
    __syncthreads();
    for (int nn = w; nn < 64; nn += 4) {
        int nw = n0 + nn;
        if (nw < NN) xT[(size_t)nw * 64 + lane] = t[lane][nn];
    }
}

__global__ void k_count(const int* __restrict__ src, const int* __restrict__ dst,
                        int* __restrict__ cs, int* __restrict__ cd) {
    int e = blockIdx.x * blockDim.x + threadIdx.x;
    if (e >= NE) return;
    atomicAdd(&cs[src[e]], 1);
    int d = dst[e];
    if (d >= NI && d < NI + NF) atomicAdd(&cd[d - NI], 1);
}

__global__ void k_scan(const int* __restrict__ cnt, int* __restrict__ rp, int L) {
    __shared__ int tsum[1024];
    int t = threadIdx.x;
    int per = (L + 1023) >> 10;
    int beg = t * per;
    int end = beg + per; if (end > L) end = L;
    int s = 0;
    for (int i = beg; i < end; ++i) s += cnt[i];
    tsum[t] = s;
    __syncthreads();
    for (int off = 1; off < 1024; off <<= 1) {
        int v = (t >= off) ? tsum[t - off] : 0;
        __syncthreads();
        tsum[t] += v;
        __syncthreads();
    }
    int run = (t == 0) ? 0 : tsum[t - 1];
    for (int i = beg; i < end; ++i) { rp[i] = run; run += cnt[i]; }
    if (t == 1023) rp[L] = tsum[1023];
}

__global__ void k_copyoff(const int* __restrict__ rp_s, const int* __restrict__ rp_d,
                          int* __restrict__ off_s, int* __restrict__ off_d,
                          int* __restrict__ foCtr) {
    int i = blockIdx.x * blockDim.x + threadIdx.x;
    if (i < NS) off_s[i] = rp_s[i];
    if (i < NF) off_d[i] = rp_d[i];
    if (i == 0) foCtr[0] = rp_d[NF];
}

__global__ void k_fill(const int* __restrict__ src, const int* __restrict__ dst,
                       int* __restrict__ off_s, int* __restrict__ off_d,
                       int* __restrict__ foCtr,
                       int* __restrict__ el_s, int* __restrict__ el_d,
                       int* __restrict__ posOf) {
    int e = blockIdx.x * blockDim.x + threadIdx.x;
    if (e >= NE) return;
    int p = atomicAdd(&off_s[src[e]], 1);
    el_s[p] = e;
    int d = dst[e];
    int q;
    if (d >= NI && d < NI + NF) {
        q = atomicAdd(&off_d[d - NI], 1);
        el_d[q] = e;
    } else {
        q = atomicAdd(foCtr, 1);   // fo edges: slots after rp_d[NF]
    }
    posOf[e] = q;
}

// Build CSR-ordered streams (once per call).
// pd[k]  (dst order): (off<<1)|normflag ; off = src*64 (input src) or XEBASE+k*64
// pe2[k] (src order): posOf(e)*64
// c3[k]  (src order): b3[e] + dot(elu(b2[src]), w3row) for input-src edges
__global__ void k_permute(const int* __restrict__ src,
                          const float* __restrict__ w1, const float* __restrict__ w3,
                          const float* __restrict__ b3, const float* __restrict__ b2,
                          const int* __restrict__ rp_d,
                          const int* __restrict__ el_d, const int* __restrict__ el_s,
                          const int* __restrict__ posOf,
                          unsigned* __restrict__ pd, unsigned* __restrict__ pe2,
                          float* __restrict__ w1g, float* __restrict__ w3g,
                          float* __restrict__ b3g, float* __restrict__ c3) {
    int k = blockIdx.x * blockDim.x + threadIdx.x;
    if (k >= NE) return;
    {
        int e = el_s[k];
        int s = src[e];
        pe2[k] = (unsigned)(posOf[e] * NB);
        float wrow[NC];
        const f32x4* s4 = (const f32x4*)(w3 + (size_t)e * NC);
        ((f32x4*)wrow)[0] = s4[0]; ((f32x4*)wrow)[1] = s4[1];
        ((f32x4*)wrow)[2] = s4[2]; ((f32x4*)wrow)[3] = s4[3];
        f32x4* d4 = (f32x4*)(w3g + (size_t)k * NC);
        d4[0] = ((f32x4*)wrow)[0]; d4[1] = ((f32x4*)wrow)[1];
        d4[2] = ((f32x4*)wrow)[2]; d4[3] = ((f32x4*)wrow)[3];
        float bb = b3[e];
        b3g[k] = bb;
        float cc = 0.f;
        if (s < NI) {
            const float* b2r = b2 + (size_t)s * NC;
            #pragma unroll
            for (int c = 0; c < NC; ++c) {
                float h = b2r[c];
                h = h > 0.f ? h : __expf(h) - 1.0f;
                cc += h * wrow[c];
            }
            cc += bb;
        }
        c3[k] = cc;
    }
    if (k < rp_d[NF]) {
        int e = el_d[k];
        int s = src[e];
        unsigned off = (s < NI) ? (unsigned)(s * NB) : (unsigned)(XEBASE + k * NB);
        pd[k] = (off << 1) | (s < NI ? 0u : 1u);
        const f32x4* s4 = (const f32x4*)(w1 + (size_t)e * NC);
        f32x4* d4 = (f32x4*)(w1g + (size_t)k * NC);
        d4[0] = s4[0]; d4[1] = s4[1]; d4[2] = s4[2]; d4[3] = s4[3];
    }
}

// xeD[posOf(e)] = x0(src[e]); accum slot0 = identity stats, rest 0
__global__ void k_init_xe(const float* __restrict__ xbuf, const int* __restrict__ src,
                          const int* __restrict__ posOf,
                          float* __restrict__ xeD, float* __restrict__ accum) {
    size_t idx = (size_t)blockIdx.x * blockDim.x + threadIdx.x;
    if (idx < (NLAYERS + 1) * 128) {
        float v = 0.f;
        if (idx >= 64 && idx < 128) v = (float)NE * (1.0f - LN_EPS);
        accum[idx] = v;
    }
    if (idx >= (size_t)NE * NB) return;
    int e = (int)(idx >> 6), b = (int)(idx & 63);
    float v = xbuf[(size_t)src[e] * NB + b];
    __builtin_nontemporal_store(v, &xeD[(size_t)posOf[e] * NB + b]);
}

// Per fn node (one wave, lane=batch): stream in-edge messages in dst-CSR order,
// 16-deep gather batch for MLP; elu(+b1), 16x16 w2, elu(+b2) -> h2 row (NT).
__global__ __launch_bounds__(256, 4) void k_node(
    const float* __restrict__ xbuf, const float* __restrict__ sums,
    const float* __restrict__ w1g, const float* __restrict__ b1,
    const float* __restrict__ w2, const float* __restrict__ b2,
    const int* __restrict__ rp, const unsigned* __restrict__ pd,
    float* __restrict__ h2)
{
    int wid = __builtin_amdgcn_readfirstlane((int)((blockIdx.x * blockDim.x + threadIdx.x) >> 6));
    int lane = threadIdx.x & 63;
    if (wid >= NF) return;
    const float inv = 1.0f / (float)NE;
    float mu = sums[lane] * inv;
    float rs = rsqrtf(sums[64 + lane] * inv - mu * mu + LN_EPS);

    int n = NI + wid;
    float acc[NC];
    {
        const f32x4* b1r = (const f32x4*)(b1 + (size_t)n * NC);
        f32x4 a = b1r[0], b = b1r[1], c = b1r[2], d = b1r[3];
        acc[0]=a.x; acc[1]=a.y; acc[2]=a.z; acc[3]=a.w;
        acc[4]=b.x; acc[5]=b.y; acc[6]=b.z; acc[7]=b.w;
        acc[8]=c.x; acc[9]=c.y; acc[10]=c.z; acc[11]=c.w;
        acc[12]=d.x; acc[13]=d.y; acc[14]=d.z; acc[15]=d.w;
    }

    int k0 = __builtin_amdgcn_readfirstlane(rp[wid]);
    int k1 = __builtin_amdgcn_readfirstlane(rp[wid + 1]);

    for (int base = k0; base < k1; base += PF) {
        int m = k1 - base; if (m > PF) m = PF;
        unsigned pv[PF];
        #pragma unroll
        for (int j = 0; j < PF; ++j) pv[j] = (j < m) ? pd[base + j] : 0u;
        float raw[PF];
        #pragma unroll
        for (int j = 0; j < PF; ++j)
            if (j < m) raw[j] = xbuf[(size_t)(pv[j] >> 1) + lane];
        #pragma unroll
        for (int j = 0; j < PF; ++j) {
            if (j < m) {
                float xv = (pv[j] & 1u) ? (raw[j] - mu) * rs : raw[j];
                const f32x4* wr = (const f32x4*)(w1g + (size_t)(base + j) * NC);
                f32x4 a = wr[0], b = wr[1], c = wr[2], d = wr[3];
                acc[0]  += xv * a.x; acc[1]  += xv * a.y; acc[2]  += xv * a.z; acc[3]  += xv * a.w;
                acc[4]  += xv * b.x; acc[5]  += xv * b.y; acc[6]  += xv * b.z; acc[7]  += xv * b.w;
                acc[8]  += xv * c.x; acc[9]  += xv * c.y; acc[10] += xv * c.z; acc[11] += xv * c.w;
                acc[12] += xv * d.x; acc[13] += xv * d.y; acc[14] += xv * d.z; acc[15] += xv * d.w;
            }
        }
    }

    float h[NC];
    #pragma unroll
    for (int c = 0; c < NC; ++c) h[c] = elu_fast(acc[c]);

    float hf[NC];
    {
        const f32x4* b2r = (const f32x4*)(b2 + (size_t)n * NC);
        f32x4 a = b2r[0], b = b2r[1], c = b2r[2], d = b2r[3];
        hf[0]=a.x; hf[1]=a.y; hf[2]=a.z; hf[3]=a.w;
        hf[4]=b.x; hf[5]=b.y; hf[6]=b.z; hf[7]=b.w;
        hf[8]=c.x; hf[9]=c.y; hf[10]=c.z; hf[11]=c.w;
        hf[12]=d.x; hf[13]=d.y; hf[14]=d.z; hf[15]=d.w;
    }
    const float* w2f = w2 + (size_t)wid * NC * NC;
    #pragma unroll
    for (int c = 0; c < NC; ++c) {
        const f32x4* w2r = (const f32x4*)(w2f + c * NC);
        f32x4 a = w2r[0], b = w2r[1], cc = w2r[2], d = w2r[3];
        float hc = h[c];
        hf[0]  += hc * a.x;  hf[1]  += hc * a.y;  hf[2]  += hc * a.z;  hf[3]  += hc * a.w;
        hf[4]  += hc * b.x;  hf[5]  += hc * b.y;  hf[6]  += hc * b.z;  hf[7]  += hc * b.w;
        hf[8]  += hc * cc.x; hf[9]  += hc * cc.y; hf[10] += hc * cc.z; hf[11] += hc * cc.w;
        hf[12] += hc * d.x;  hf[13] += hc * d.y;  hf[14] += hc * d.z;  hf[15] += hc * d.w;
    }

    f32x4 o0, o1, o2, o3;
    o0.x = elu_fast(hf[0]);  o0.y = elu_fast(hf[1]);
    o0.z = elu_fast(hf[2]);  o0.w = elu_fast(hf[3]);
    o1.x = elu_fast(hf[4]);  o1.y = elu_fast(hf[5]);
    o1.z = elu_fast(hf[6]);  o1.w = elu_fast(hf[7]);
    o2.x = elu_fast(hf[8]);  o2.y = elu_fast(hf[9]);
    o2.z = elu_fast(hf[10]); o2.w = elu_fast(hf[11]);
    o3.x = elu_fast(hf[12]); o3.y = elu_fast(hf[13]);
    o3.z = elu_fast(hf[14]); o3.w = elu_fast(hf[15]);
    f32x4* h2r = (f32x4*)(h2 + ((size_t)wid * NB + lane) * NC);
    __builtin_nontemporal_store(o0, h2r + 0);
    __builtin_nontemporal_store(o1, h2r + 1);
    __builtin_nontemporal_store(o2, h2r + 2);
    __builtin_nontemporal_store(o3, h2r + 3);
}

// Per src node (one wave, lane=batch): h2 row reused across out-edges,
// 16-deep gather batch of prev-layer xe values for MLP.
__global__ __launch_bounds__(512, 4) void k_edge(
    float* __restrict__ xeD, const float* __restrict__ xT,
    const float* __restrict__ sums, float* __restrict__ sumsOut,
    const float* __restrict__ h2,
    const float* __restrict__ w3g, const float* __restrict__ b3g,
    const float* __restrict__ c3,
    const int* __restrict__ rp, const unsigned* __restrict__ pe2)
{
    __shared__ float shs[512], shq[512];
    int lane = threadIdx.x & 63;
    int s = __builtin_amdgcn_readfirstlane((int)(blockIdx.x * 8 + (threadIdx.x >> 6)));
    float lsum = 0.f, lsq = 0.f;
    if (s < NS) {
        float x0v = xT[(size_t)s * NB + lane];
        int k0 = __builtin_amdgcn_readfirstlane(rp[s]);
        int k1 = __builtin_amdgcn_readfirstlane(rp[s + 1]);
        if (s < NI) {
            // all out-edges are input edges: v = x0 + precomputed const
            for (int k = k0; k < k1; ++k) {
                float v = x0v + c3[k];
                lsum += v; lsq += v * v;
            }
        } else {
            const float inv = 1.0f / (float)NE;
            float mu = sums[lane] * inv;
            float rs = rsqrtf(sums[64 + lane] * inv - mu * mu + LN_EPS);
            float hv[NC];
            {
                const f32x4* hr = (const f32x4*)(h2 + (((size_t)(s - NI)) * NB + lane) * NC);
                f32x4 a = __builtin_nontemporal_load(hr + 0);
                f32x4 b = __builtin_nontemporal_load(hr + 1);
                f32x4 c = __builtin_nontemporal_load(hr + 2);
                f32x4 d = __builtin_nontemporal_load(hr + 3);
                hv[0]=a.x; hv[1]=a.y; hv[2]=a.z; hv[3]=a.w;
                hv[4]=b.x; hv[5]=b.y; hv[6]=b.z; hv[7]=b.w;
                hv[8]=c.x; hv[9]=c.y; hv[10]=c.z; hv[11]=c.w;
                hv[12]=d.x; hv[13]=d.y; hv[14]=d.z; hv[15]=d.w;
            }
            for (int base = k0; base < k1; base += PF) {
                int m = k1 - base; if (m > PF) m = PF;
                unsigned pos[PF];
                #pragma unroll
                for (int j = 0; j < PF; ++j) pos[j] = (j < m) ? pe2[base + j] : 0u;
                float old[PF];
                #pragma unroll
                for (int j = 0; j < PF; ++j)
                    if (j < m) old[j] = xeD[(size_t)pos[j] + lane];
                #pragma unroll
                for (int j = 0; j < PF; ++j) {
                    if (j < m) {
                        float xl = (old[j] - mu) * rs;   // all unmasked here
                        const f32x4* wr = (const f32x4*)(w3g + (size_t)(base + j) * NC);
                        f32x4 a = wr[0], b = wr[1], c = wr[2], d = wr[3];
                        float v = b3g[base + j] + xl;
                        v += hv[0]*a.x + hv[1]*a.y + hv[2]*a.z + hv[3]*a.w;
                        v += hv[4]*b.x + hv[5]*b.y + hv[6]*b.z + hv[7]*b.w;
                        v += hv[8]*c.x + hv[9]*c.y + hv[10]*c.z + hv[11]*c.w;
                        v += hv[12]*d.x + hv[13]*d.y + hv[14]*d.z + hv[15]*d.w;
                        __builtin_nontemporal_store(v, &xeD[(size_t)pos[j] + lane]);
                        lsum += v; lsq += v * v;
                    }
                }
            }
        }
    }
    shs[threadIdx.x] = lsum; shq[threadIdx.x] = lsq;
    __syncthreads();
    int t = threadIdx.x;
    if (t < 64) {
        float ts = 0.f;
        #pragma unroll
        for (int w = 0; w < 8; ++w) ts += shs[w * 64 + t];
        atomicAdd(&sumsOut[t], ts);
    } else if (t < 128) {
        int l = t - 64;
        float tq = 0.f;
        #pragma unroll
        for (int w = 0; w < 8; ++w) tq += shq[w * 64 + l];
        atomicAdd(&sumsOut[64 + l], tq);
    }
}

__global__ __launch_bounds__(256) void k_out(
    const float* __restrict__ xbuf, const float* __restrict__ sums,
    const int* __restrict__ src, const int* __restrict__ posOf,
    const float* __restrict__ scale, const float* __restrict__ bias,
    const int* __restrict__ last_edge, const float* __restrict__ has,
    float* __restrict__ out)
{
    __shared__ float t[64][65];
    int n0 = blockIdx.x * 64;
    int lane = threadIdx.x & 63, w = threadIdx.x >> 6;
    const float inv = 1.0f / (float)NE;
    float mu = sums[lane] * inv;
    float rs = rsqrtf(sums[64 + lane] * inv - mu * mu + LN_EPS);
    for (int nn = w; nn < 64; nn += 4) {
        int n = n0 + nn;
        float val = 0.f;
        if (n < NN) {
            int le = last_edge[n];
            int s = src[le];
            float x0v = xbuf[(size_t)s * NB + lane];
            float xn = (xbuf[(size_t)XEBASE + (size_t)posOf[le] * NB + lane] - mu) * rs;
            float xf = (s < NI) ? x0v : xn;
            val = has[n] * (scale[le] * xf + bias[le]);
        }
        t[nn][lane] = val;
    }
    __syncthreads();
    for (int bb = w; bb < 64; bb += 4) {
        int n = n0 + lane;
        if (n < NN) out[(size_t)bb * NN + n] = t[lane][bb];
    }
}

extern "C" void kernel_launch(void* const* d_in, const int* in_sizes, int n_in,
                              void* d_out, int out_size, void* d_ws, size_t ws_size,
                              hipStream_t stream) {
    const float* x     = (const float*)d_in[0];
    const float* w1    = (const float*)d_in[1];
    const float* b1    = (const float*)d_in[2];
    const float* w2    = (const float*)d_in[3];
    const float* b2    = (const float*)d_in[4];
    const float* w3    = (const float*)d_in[5];
    const float* b3    = (const float*)d_in[6];
    const float* scale = (const float*)d_in[7];
    const float* bias  = (const float*)d_in[8];
    const int*   src   = (const int*)d_in[9];
    const int*   dst   = (const int*)d_in[10];
    const int*   last  = (const int*)d_in[13];
    const float* has   = (const float*)d_in[14];
    float* out = (float*)d_out;

    char* p = (char*)d_ws;
    auto alloc = [&](size_t bytes) {
        char* r = p;
        p += (bytes + 255) & ~(size_t)255;
        return r;
    };
    float* xbuf  = (float*)alloc(((size_t)NN + NE) * NB * 4);   // [xT | xeD]
    float* xeD   = xbuf + XEBASE;
    float* h2    = (float*)alloc((size_t)NF * NB * NC * 4);
    float* accum = (float*)alloc((NLAYERS + 1) * 128 * 4);
    float* w1g   = (float*)alloc((size_t)NE * NC * 4);
    float* w3g   = (float*)alloc((size_t)NE * NC * 4);
    float* b3g   = (float*)alloc((size_t)NE * 4);
    float* c3    = (float*)alloc((size_t)NE * 4);
    unsigned* pd  = (unsigned*)alloc((size_t)NE * 4);
    unsigned* pe2 = (unsigned*)alloc((size_t)NE * 4);
    int* rp_s  = (int*)alloc((NS + 1) * 4);
    int* rp_d  = (int*)alloc((NF + 1) * 4);
    int* el_s  = (int*)alloc((size_t)NE * 4);
    int* el_d  = (int*)alloc((size_t)NE * 4);
    int* posOf = (int*)alloc((size_t)NE * 4);
    int* off_s = (int*)alloc(NS * 4);
    int* off_d = (int*)alloc(NF * 4);
    int* cs    = (int*)alloc(NS * 4);
    int* cd    = (int*)alloc(NF * 4);
    int* foCtr = (int*)alloc(4);

    hipMemsetAsync(cs, 0, NS * 4, stream);
    hipMemsetAsync(cd, 0, NF * 4, stream);
    k_transpose<<<TILE_BLOCKS, 256, 0, stream>>>(x, xbuf);
    k_count<<<(NE + 255) / 256, 256, 0, stream>>>(src, dst, cs, cd);
    k_scan<<<1, 1024, 0, stream>>>(cs, rp_s, NS);
    k_scan<<<1, 1024, 0, stream>>>(cd, rp_d, NF);
    k_copyoff<<<(NS + 255) / 256, 256, 0, stream>>>(rp_s, rp_d, off_s, off_d, foCtr);
    k_fill<<<(NE + 255) / 256, 256, 0, stream>>>(src, dst, off_s, off_d, foCtr,
                                                 el_s, el_d, posOf);
    k_permute<<<(NE + 255) / 256, 256, 0, stream>>>(src, w1, w3, b3, b2, rp_d,
                                                    el_d, el_s, posOf,
                                                    pd, pe2, w1g, w3g, b3g, c3);
    k_init_xe<<<(int)(((size_t)NE * NB + 255) / 256), 256, 0, stream>>>(xbuf, src, posOf,
                                                                        xeD, accum);

    for (int L = 0; L < NLAYERS; ++L) {
        k_node<<<NODE_BLOCKS, 256, 0, stream>>>(xbuf, accum + L * 128,
                                                w1g, b1, w2, b2, rp_d, pd, h2);
        k_edge<<<EDGE_BLOCKS, 512, 0, stream>>>(xeD, xbuf, accum + L * 128,
                                                accum + (L + 1) * 128,
                                                h2, w3g, b3g, c3, rp_s, pe2);
    }
    k_out<<<TILE_BLOCKS, 256, 0, stream>>>(xbuf, accum + NLAYERS * 128, src, posOf,
                                           scale, bias, last, has, out);
}

// Round 6
// 378.501 us; speedup vs baseline: 1.4997x; 1.4997x over previous
//
#include <hip/hip_runtime.h>
#include <math.h>

#define NN 10000
#define NI 1000
#define NF 8600
#define NE 80000
#define NC 16
#define NB 64
#define NS (NI + NF)        // 9600 possible src nodes
#define NLAYERS 6
#define LN_EPS 1e-5f
#define PF 8                // gather batch depth

#define LAYER_BLOCKS ((NS + 7) / 8)      // 1200 blocks x 8 waves
#define TILE_BLOCKS ((NN + 63) / 64)     // 157

typedef float f32x4 __attribute__((ext_vector_type(4)));

__device__ __forceinline__ float elu_fast(float x) {
    return x > 0.0f ? x : __expf(x) - 1.0f;
}

// ---- tiled transpose: xT[n*64+b] = x[b*NN+n] ----
__global__ __launch_bounds__(256) void k_transpose(const float* __restrict__ x,
                                                   float* __restrict__ xT) {
    __shared__ float t[64][65];
    int n0 = blockIdx.x * 64;
    int lane = threadIdx.x & 63, w = threadIdx.x >> 6;
    int n = n0 + lane;
    for (int bb = w; bb < 64; bb += 4)
        t[bb][lane] = (n < NN) ? x[(size_t)bb * NN + n] : 0.f;
    __syncthreads();
    for (int nn = w; nn < 64; nn += 4) {
        int nw = n0 + nn;
        if (nw < NN) xT[(size_t)nw * 64 + lane] = t[lane][nn];
    }
}

__global__ void k_count(const int* __restrict__ src, const int* __restrict__ dst,
                        int* __restrict__ cs, int* __restrict__ cd) {
    int e = blockIdx.x * blockDim.x + threadIdx.x;
    if (e >= NE) return;
    atomicAdd(&cs[src[e]], 1);
    int d = dst[e];
    if (d >= NI && d < NI + NF) atomicAdd(&cd[d - NI], 1);
}

__global__ void k_scan(const int* __restrict__ cnt, int* __restrict__ rp, int L) {
    __shared__ int tsum[1024];
    int t = threadIdx.x;
    int per = (L + 1023) >> 10;
    int beg = t * per;
    int end = beg + per; if (end > L) end = L;
    int s = 0;
    for (int i = beg; i < end; ++i) s += cnt[i];
    tsum[t] = s;
    __syncthreads();
    for (int off = 1; off < 1024; off <<= 1) {
        int v = (t >= off) ? tsum[t - off] : 0;
        __syncthreads();
        tsum[t] += v;
        __syncthreads();
    }
    int run = (t == 0) ? 0 : tsum[t - 1];
    for (int i = beg; i < end; ++i) { rp[i] = run; run += cnt[i]; }
    if (t == 1023) rp[L] = tsum[1023];
}

__global__ void k_copyoff(const int* __restrict__ rp_s, const int* __restrict__ rp_d,
                          int* __restrict__ off_s, int* __restrict__ off_d,
                          int* __restrict__ foCtr) {
    int i = blockIdx.x * blockDim.x + threadIdx.x;
    if (i < NS) off_s[i] = rp_s[i];
    if (i < NF) off_d[i] = rp_d[i];
    if (i == 0) foCtr[0] = rp_d[NF];
}

__global__ void k_fill(const int* __restrict__ src, const int* __restrict__ dst,
                       int* __restrict__ off_s, int* __restrict__ off_d,
                       int* __restrict__ foCtr,
                       int* __restrict__ el_s, int* __restrict__ el_d,
                       int* __restrict__ posOf) {
    int e = blockIdx.x * blockDim.x + threadIdx.x;
    if (e >= NE) return;
    int p = atomicAdd(&off_s[src[e]], 1);
    el_s[p] = e;
    int d = dst[e];
    int q;
    if (d >= NI && d < NI + NF) {
        q = atomicAdd(&off_d[d - NI], 1);
        el_d[q] = e;
    } else {
        q = atomicAdd(foCtr, 1);   // fo edges: slots after rp_d[NF]
    }
    posOf[e] = q;
}

// pd[k] (dst order): (off<<1)|flag; flag=1: off = k*64 into xe region (norm),
//                                  flag=0: off = s*64 into xT (pinned x0)
// pe2[k] (src order): posOf(e)*64 (xe-region-relative)
// c3[k]  (src order): b3[e] + dot(elu(b2[src]), w3row) for input-src edges
__global__ void k_permute(const int* __restrict__ src,
                          const float* __restrict__ w1, const float* __restrict__ w3,
                          const float* __restrict__ b3, const float* __restrict__ b2,
                          const int* __restrict__ rp_d,
                          const int* __restrict__ el_d, const int* __restrict__ el_s,
                          const int* __restrict__ posOf,
                          unsigned* __restrict__ pd, unsigned* __restrict__ pe2,
                          float* __restrict__ w1g, float* __restrict__ w3g,
                          float* __restrict__ b3g, float* __restrict__ c3) {
    int k = blockIdx.x * blockDim.x + threadIdx.x;
    if (k >= NE) return;
    {
        int e = el_s[k];
        int s = src[e];
        pe2[k] = (unsigned)(posOf[e] * NB);
        float wrow[NC];
        const f32x4* s4 = (const f32x4*)(w3 + (size_t)e * NC);
        ((f32x4*)wrow)[0] = s4[0]; ((f32x4*)wrow)[1] = s4[1];
        ((f32x4*)wrow)[2] = s4[2]; ((f32x4*)wrow)[3] = s4[3];
        f32x4* d4 = (f32x4*)(w3g + (size_t)k * NC);
        d4[0] = ((f32x4*)wrow)[0]; d4[1] = ((f32x4*)wrow)[1];
        d4[2] = ((f32x4*)wrow)[2]; d4[3] = ((f32x4*)wrow)[3];
        float bb = b3[e];
        b3g[k] = bb;
        float cc = 0.f;
        if (s < NI) {
            const float* b2r = b2 + (size_t)s * NC;
            #pragma unroll
            for (int c = 0; c < NC; ++c) {
                float h = b2r[c];
                h = h > 0.f ? h : __expf(h) - 1.0f;
                cc += h * wrow[c];
            }
            cc += bb;
        }
        c3[k] = cc;
    }
    if (k < rp_d[NF]) {
        int e = el_d[k];
        int s = src[e];
        unsigned off = (s < NI) ? (unsigned)(s * NB) : (unsigned)(k * NB);
        pd[k] = (off << 1) | (s < NI ? 0u : 1u);
        const f32x4* s4 = (const f32x4*)(w1 + (size_t)e * NC);
        f32x4* d4 = (f32x4*)(w1g + (size_t)k * NC);
        d4[0] = s4[0]; d4[1] = s4[1]; d4[2] = s4[2]; d4[3] = s4[3];
    }
}

// xeA[posOf(e)] = x0(src[e]); accum slot0 = identity stats, rest 0
__global__ void k_init_xe(const float* __restrict__ xT, const int* __restrict__ src,
                          const int* __restrict__ posOf,
                          float* __restrict__ xeA, float* __restrict__ accum) {
    size_t idx = (size_t)blockIdx.x * blockDim.x + threadIdx.x;
    if (idx < (NLAYERS + 1) * 128) {
        float v = 0.f;
        if (idx >= 64 && idx < 128) v = (float)NE * (1.0f - LN_EPS);
        accum[idx] = v;
    }
    if (idx >= (size_t)NE * NB) return;
    int e = (int)(idx >> 6), b = (int)(idx & 63);
    xeA[(size_t)posOf[e] * NB + b] = xT[(size_t)src[e] * NB + b];
}

// Fused layer: one wave per src node s.
//  phase 1 (s>=NI): accumulate in-edges (dst-CSR) with w1g -> elu(+b1)
//                   -> 16x16 w2 -> elu(+b2) = h2 row, kept in REGISTERS.
//  phase 2: for each out-edge (src-CSR): v = dot(h2,w3g)+b3g+norm(xe_old),
//           store to xeW. Input nodes use precomputed c3 (no store needed).
//  LN partial sums reduced in LDS, atomically added to sumsOut.
__global__ __launch_bounds__(512, 4) void k_layer(
    const float* __restrict__ xT,
    const float* __restrict__ xeR, float* __restrict__ xeW,
    const float* __restrict__ sums, float* __restrict__ sumsOut,
    const float* __restrict__ w1g, const float* __restrict__ b1,
    const float* __restrict__ w2, const float* __restrict__ b2,
    const float* __restrict__ w3g, const float* __restrict__ b3g,
    const float* __restrict__ c3,
    const int* __restrict__ rp_d, const unsigned* __restrict__ pd,
    const int* __restrict__ rp_s, const unsigned* __restrict__ pe2)
{
    __shared__ float shs[512], shq[512];
    int lane = threadIdx.x & 63;
    int s = __builtin_amdgcn_readfirstlane((int)(blockIdx.x * 8 + (threadIdx.x >> 6)));
    float lsum = 0.f, lsq = 0.f;
    if (s < NS) {
        int k0s = __builtin_amdgcn_readfirstlane(rp_s[s]);
        int k1s = __builtin_amdgcn_readfirstlane(rp_s[s + 1]);
        if (s < NI) {
            float x0v = xT[(size_t)s * NB + lane];
            for (int k = k0s; k < k1s; ++k) {
                float v = x0v + c3[k];
                lsum += v; lsq += v * v;
            }
        } else {
            const float inv = 1.0f / (float)NE;
            float mu = sums[lane] * inv;
            float rs = rsqrtf(sums[64 + lane] * inv - mu * mu + LN_EPS);
            int f = s - NI;

            // ---- phase 1: in-edge accumulation ----
            float acc[NC];
            {
                const f32x4* b1r = (const f32x4*)(b1 + (size_t)s * NC);
                f32x4 a = b1r[0], b = b1r[1], c = b1r[2], d = b1r[3];
                acc[0]=a.x; acc[1]=a.y; acc[2]=a.z; acc[3]=a.w;
                acc[4]=b.x; acc[5]=b.y; acc[6]=b.z; acc[7]=b.w;
                acc[8]=c.x; acc[9]=c.y; acc[10]=c.z; acc[11]=c.w;
                acc[12]=d.x; acc[13]=d.y; acc[14]=d.z; acc[15]=d.w;
            }
            int k0d = __builtin_amdgcn_readfirstlane(rp_d[f]);
            int k1d = __builtin_amdgcn_readfirstlane(rp_d[f + 1]);
            for (int base = k0d; base < k1d; base += PF) {
                int m = k1d - base; if (m > PF) m = PF;
                unsigned pv[PF];
                #pragma unroll
                for (int j = 0; j < PF; ++j) pv[j] = (j < m) ? pd[base + j] : 0u;
                float raw[PF];
                #pragma unroll
                for (int j = 0; j < PF; ++j)
                    if (j < m) {
                        const float* bp = (pv[j] & 1u) ? xeR : xT;
                        raw[j] = bp[(size_t)(pv[j] >> 1) + lane];
                    }
                #pragma unroll
                for (int j = 0; j < PF; ++j) {
                    if (j < m) {
                        float xv = (pv[j] & 1u) ? (raw[j] - mu) * rs : raw[j];
                        const f32x4* wr = (const f32x4*)(w1g + (size_t)(base + j) * NC);
                        f32x4 a = wr[0], b = wr[1], c = wr[2], d = wr[3];
                        acc[0]  += xv * a.x; acc[1]  += xv * a.y; acc[2]  += xv * a.z; acc[3]  += xv * a.w;
                        acc[4]  += xv * b.x; acc[5]  += xv * b.y; acc[6]  += xv * b.z; acc[7]  += xv * b.w;
                        acc[8]  += xv * c.x; acc[9]  += xv * c.y; acc[10] += xv * c.z; acc[11] += xv * c.w;
                        acc[12] += xv * d.x; acc[13] += xv * d.y; acc[14] += xv * d.z; acc[15] += xv * d.w;
                    }
                }
            }

            float h[NC];
            #pragma unroll
            for (int c = 0; c < NC; ++c) h[c] = elu_fast(acc[c]);

            float hf[NC];
            {
                const f32x4* b2r = (const f32x4*)(b2 + (size_t)s * NC);
                f32x4 a = b2r[0], b = b2r[1], c = b2r[2], d = b2r[3];
                hf[0]=a.x; hf[1]=a.y; hf[2]=a.z; hf[3]=a.w;
                hf[4]=b.x; hf[5]=b.y; hf[6]=b.z; hf[7]=b.w;
                hf[8]=c.x; hf[9]=c.y; hf[10]=c.z; hf[11]=c.w;
                hf[12]=d.x; hf[13]=d.y; hf[14]=d.z; hf[15]=d.w;
            }
            const float* w2f = w2 + (size_t)f * NC * NC;
            #pragma unroll
            for (int c = 0; c < NC; ++c) {
                const f32x4* w2r = (const f32x4*)(w2f + c * NC);
                f32x4 a = w2r[0], b = w2r[1], cc = w2r[2], d = w2r[3];
                float hc = h[c];
                hf[0]  += hc * a.x;  hf[1]  += hc * a.y;  hf[2]  += hc * a.z;  hf[3]  += hc * a.w;
                hf[4]  += hc * b.x;  hf[5]  += hc * b.y;  hf[6]  += hc * b.z;  hf[7]  += hc * b.w;
                hf[8]  += hc * cc.x; hf[9]  += hc * cc.y; hf[10] += hc * cc.z; hf[11] += hc * cc.w;
                hf[12] += hc * d.x;  hf[13] += hc * d.y;  hf[14] += hc * d.z;  hf[15] += hc * d.w;
            }
            float hv[NC];
            #pragma unroll
            for (int c = 0; c < NC; ++c) hv[c] = elu_fast(hf[c]);   // h2 row, in regs

            // ---- phase 2: out-edges ----
            for (int base = k0s; base < k1s; base += PF) {
                int m = k1s - base; if (m > PF) m = PF;
                unsigned pos[PF];
                #pragma unroll
                for (int j = 0; j < PF; ++j) pos[j] = (j < m) ? pe2[base + j] : 0u;
                float old[PF];
                #pragma unroll
                for (int j = 0; j < PF; ++j)
                    if (j < m) old[j] = xeR[(size_t)pos[j] + lane];
                #pragma unroll
                for (int j = 0; j < PF; ++j) {
                    if (j < m) {
                        float xl = (old[j] - mu) * rs;
                        const f32x4* wr = (const f32x4*)(w3g + (size_t)(base + j) * NC);
                        f32x4 a = wr[0], b = wr[1], c = wr[2], d = wr[3];
                        float v = b3g[base + j] + xl;
                        v += hv[0]*a.x + hv[1]*a.y + hv[2]*a.z + hv[3]*a.w;
                        v += hv[4]*b.x + hv[5]*b.y + hv[6]*b.z + hv[7]*b.w;
                        v += hv[8]*c.x + hv[9]*c.y + hv[10]*c.z + hv[11]*c.w;
                        v += hv[12]*d.x + hv[13]*d.y + hv[14]*d.z + hv[15]*d.w;
                        xeW[(size_t)pos[j] + lane] = v;
                        lsum += v; lsq += v * v;
                    }
                }
            }
        }
    }
    shs[threadIdx.x] = lsum; shq[threadIdx.x] = lsq;
    __syncthreads();
    int t = threadIdx.x;
    if (t < 64) {
        float ts = 0.f;
        #pragma unroll
        for (int w = 0; w < 8; ++w) ts += shs[w * 64 + t];
        atomicAdd(&sumsOut[t], ts);
    } else if (t < 128) {
        int l = t - 64;
        float tq = 0.f;
        #pragma unroll
        for (int w = 0; w < 8; ++w) tq += shq[w * 64 + l];
        atomicAdd(&sumsOut[64 + l], tq);
    }
}

__global__ __launch_bounds__(256) void k_out(
    const float* __restrict__ xT, const float* __restrict__ xeF,
    const float* __restrict__ sums,
    const int* __restrict__ src, const int* __restrict__ posOf,
    const float* __restrict__ scale, const float* __restrict__ bias,
    const int* __restrict__ last_edge, const float* __restrict__ has,
    float* __restrict__ out)
{
    __shared__ float t[64][65];
    int n0 = blockIdx.x * 64;
    int lane = threadIdx.x & 63, w = threadIdx.x >> 6;
    const float inv = 1.0f / (float)NE;
    float mu = sums[lane] * inv;
    float rs = rsqrtf(sums[64 + lane] * inv - mu * mu + LN_EPS);
    for (int nn = w; nn < 64; nn += 4) {
        int n = n0 + nn;
        float val = 0.f;
        if (n < NN) {
            int le = last_edge[n];
            int s = src[le];
            float x0v = xT[(size_t)s * NB + lane];
            float xn = (xeF[(size_t)posOf[le] * NB + lane] - mu) * rs;
            float xf = (s < NI) ? x0v : xn;
            val = has[n] * (scale[le] * xf + bias[le]);
        }
        t[nn][lane] = val;
    }
    __syncthreads();
    for (int bb = w; bb < 64; bb += 4) {
        int n = n0 + lane;
        if (n < NN) out[(size_t)bb * NN + n] = t[lane][bb];
    }
}

extern "C" void kernel_launch(void* const* d_in, const int* in_sizes, int n_in,
                              void* d_out, int out_size, void* d_ws, size_t ws_size,
                              hipStream_t stream) {
    const float* x     = (const float*)d_in[0];
    const float* w1    = (const float*)d_in[1];
    const float* b1    = (const float*)d_in[2];
    const float* w2    = (const float*)d_in[3];
    const float* b2    = (const float*)d_in[4];
    const float* w3    = (const float*)d_in[5];
    const float* b3    = (const float*)d_in[6];
    const float* scale = (const float*)d_in[7];
    const float* bias  = (const float*)d_in[8];
    const int*   src   = (const int*)d_in[9];
    const int*   dst   = (const int*)d_in[10];
    const int*   last  = (const int*)d_in[13];
    const float* has   = (const float*)d_in[14];
    float* out = (float*)d_out;

    char* p = (char*)d_ws;
    auto alloc = [&](size_t bytes) {
        char* r = p;
        p += (bytes + 255) & ~(size_t)255;
        return r;
    };
    float* xT    = (float*)alloc((size_t)NN * NB * 4);
    float* xeA   = (float*)alloc((size_t)NE * NB * 4);
    float* xeB   = (float*)alloc((size_t)NE * NB * 4);
    float* accum = (float*)alloc((NLAYERS + 1) * 128 * 4);
    float* w1g   = (float*)alloc((size_t)NE * NC * 4);
    float* w3g   = (float*)alloc((size_t)NE * NC * 4);
    float* b3g   = (float*)alloc((size_t)NE * 4);
    float* c3    = (float*)alloc((size_t)NE * 4);
    unsigned* pd  = (unsigned*)alloc((size_t)NE * 4);
    unsigned* pe2 = (unsigned*)alloc((size_t)NE * 4);
    int* rp_s  = (int*)alloc((NS + 1) * 4);
    int* rp_d  = (int*)alloc((NF + 1) * 4);
    int* el_s  = (int*)alloc((size_t)NE * 4);
    int* el_d  = (int*)alloc((size_t)NE * 4);
    int* posOf = (int*)alloc((size_t)NE * 4);
    int* off_s = (int*)alloc(NS * 4);
    int* off_d = (int*)alloc(NF * 4);
    int* cs    = (int*)alloc(NS * 4);
    int* cd    = (int*)alloc(NF * 4);
    int* foCtr = (int*)alloc(4);

    hipMemsetAsync(cs, 0, NS * 4, stream);
    hipMemsetAsync(cd, 0, NF * 4, stream);
    k_transpose<<<TILE_BLOCKS, 256, 0, stream>>>(x, xT);
    k_count<<<(NE + 255) / 256, 256, 0, stream>>>(src, dst, cs, cd);
    k_scan<<<1, 1024, 0, stream>>>(cs, rp_s, NS);
    k_scan<<<1, 1024, 0, stream>>>(cd, rp_d, NF);
    k_copyoff<<<(NS + 255) / 256, 256, 0, stream>>>(rp_s, rp_d, off_s, off_d, foCtr);
    k_fill<<<(NE + 255) / 256, 256, 0, stream>>>(src, dst, off_s, off_d, foCtr,
                                                 el_s, el_d, posOf);
    k_permute<<<(NE + 255) / 256, 256, 0, stream>>>(src, w1, w3, b3, b2, rp_d,
                                                    el_d, el_s, posOf,
                                                    pd, pe2, w1g, w3g, b3g, c3);
    k_init_xe<<<(int)(((size_t)NE * NB + 255) / 256), 256, 0, stream>>>(xT, src, posOf,
                                                                        xeA, accum);

    for (int L = 0; L < NLAYERS; ++L) {
        const float* xeR = (L & 1) ? xeB : xeA;
        float*       xeW = (L & 1) ? xeA : xeB;
        k_layer<<<LAYER_BLOCKS, 512, 0, stream>>>(xT, xeR, xeW,
                                                  accum + L * 128, accum + (L + 1) * 128,
                                                  w1g, b1, w2, b2, w3g, b3g, c3,
                                                  rp_d, pd, rp_s, pe2);
    }
    // NLAYERS=6 even: L5 reads xeB, writes xeA -> final is xeA
    k_out<<<TILE_BLOCKS, 256, 0, stream>>>(xT, xeA, accum + NLAYERS * 128, src, posOf,
                                           scale, bias, last, has, out);
}